// Round 3
// baseline (72.592 us; speedup 1.0000x reference)
//
#include <hip/hip_runtime.h>
#include <math.h>

#define PI_F 3.14159265358979323846f

// 16-amp half-state per thread; qubit bits: 8=q1, 4=q2, 2=q3, 1=q4.

// RX on stride-S qubit: [[c,-is],[-is,c]]
template<int S>
__device__ __forceinline__ void rx16(float* sr, float* si, float c, float s) {
#pragma unroll
    for (int i = 0; i < 16; ++i) {
        if (i & S) continue;
        const int j = i + S;
        const float r0 = sr[i], m0 = si[i], r1 = sr[j], m1 = si[j];
        sr[i] = fmaf(c, r0,  s * m1);
        si[i] = fmaf(c, m0, -s * r1);
        sr[j] = fmaf(c, r1,  s * m0);
        si[j] = fmaf(c, m1, -s * r0);
    }
}

// CX^e, control stride Sc, target stride St. B=(1-lam)/2; A+B=1:
// u = B*(a1-a0); new0 = a0+u; new1 = a1-u.
template<int Sc, int St>
__device__ __forceinline__ void cx16(float* sr, float* si, float br, float bi) {
#pragma unroll
    for (int i = 0; i < 16; ++i) {
        if (!(i & Sc) || (i & St)) continue;
        const int j = i + St;
        const float dr = sr[j] - sr[i], di = si[j] - si[i];
        const float ur = br * dr - bi * di;
        const float ui = fmaf(br, di, bi * dr);
        sr[i] += ur; si[i] += ui;
        sr[j] -= ur; si[j] -= ui;
    }
}

// Phase (cl,sl) applied to the q1=1 half (bit 8). Pass (1,0) for identity.
__device__ __forceinline__ void cz16(float* sr, float* si, float cl, float sl) {
#pragma unroll
    for (int m = 0; m < 16; ++m) {
        if (!(m & 8)) continue;
        const float r = sr[m], q = si[m];
        sr[m] = r * cl - q * sl;
        si[m] = fmaf(r, sl, q * cl);
    }
}

// B = (1 - e^{i*pi*e})/2 via hw trig (revolutions: sin(pi*e) = v_sin(e/2)).
__device__ __forceinline__ void bcoef(float e, float& br, float& bi) {
    const float rev = e * 0.5f;
    const float sl = __builtin_amdgcn_sinf(rev);
    const float cl = __builtin_amdgcn_cosf(rev);
    br = 0.5f * (1.0f - cl);
    bi = -0.5f * sl;
}

__global__ __launch_bounds__(256)
void u1_split_kernel(const float* __restrict__ inp,   // (32,32,32,3)
                     const float* __restrict__ ker,   // (8,1,15)
                     float* __restrict__ out,         // (32,31,31,8)
                     int nsim) {
    const int t   = blockIdx.x * blockDim.x + threadIdx.x;
    const int sim = t >> 1;        // lane pair (2s, 2s+1) handles simulation s
    if (sim >= nsim) return;
    const int h   = t & 1;         // 0: psi0 half, 1: psi1 half

    const int r   = sim & 7;
    const int pix = sim >> 3;
    const int iy  = pix % 31;
    const int tq  = pix / 31;
    const int ix  = tq % 31;
    const int b   = tq / 31;

    const float* xp = inp + ((size_t)(b * 32 + ix) * 32 + iy) * 3;
    const float* pp = ker + r * 15;

    // ---------- layer 0: RX product state on q1..q4 (q0 split analytically)
    float c1, s1, c2, s2, c3, s3, c4, s4;
    {
        const float a0 = xp[0], a1 = xp[3], a2 = xp[96], a3 = xp[99];
        s1 = __builtin_amdgcn_sinf(a0 * 0.25f); c1 = __builtin_amdgcn_cosf(a0 * 0.25f);
        s2 = __builtin_amdgcn_sinf(a1 * 0.25f); c2 = __builtin_amdgcn_cosf(a1 * 0.25f);
        s3 = __builtin_amdgcn_sinf(a2 * 0.25f); c3 = __builtin_amdgcn_cosf(a2 * 0.25f);
        s4 = __builtin_amdgcn_sinf(a3 * 0.25f); c4 = __builtin_amdgcn_cosf(a3 * 0.25f);
    }
    float t2[4], t3[8], mg[16];
    t2[0] = c1 * c2; t2[1] = c1 * s2; t2[2] = s1 * c2; t2[3] = s1 * s2;
#pragma unroll
    for (int x = 0; x < 8; ++x)  t3[x] = t2[x >> 1] * ((x & 1) ? s3 : c3);
#pragma unroll
    for (int x = 0; x < 16; ++x) mg[x] = t3[x >> 1] * ((x & 1) ? s4 : c4);

    // amp[m] = (-i)^popcount(m) * mg[m]  (compile-time zero pattern folds
    // into the first cx16)
    float sr[16], si[16];
#pragma unroll
    for (int m = 0; m < 16; ++m) {
        const int pc = __builtin_popcount(m) & 3;
        sr[m] = (pc == 0) ? mg[m] : ((pc == 2) ? -mg[m] : 0.0f);
        si[m] = (pc == 1) ? -mg[m] : ((pc == 3) ? mg[m] : 0.0f);
    }

    float br, bi;
    bcoef(pp[0], br, bi); cx16<8, 4>(sr, si, br, bi);
    bcoef(pp[1], br, bi); cx16<4, 2>(sr, si, br, bi);
    bcoef(pp[2], br, bi); cx16<2, 1>(sr, si, br, bi);
    bcoef(pp[3], br, bi); cx16<1, 8>(sr, si, br, bi);
    {   // CZ phases psi1 only; psi0 lane gets identity (branchless)
        const float rev = pp[4] * 0.5f;
        const float sl = __builtin_amdgcn_sinf(rev);
        const float cl = __builtin_amdgcn_cosf(rev);
        cz16(sr, si, h ? cl : 1.0f, h ? sl : 0.0f);
    }

    // ---------- layers 1..2: identical gates on both halves (this lane's own)
#pragma unroll
    for (int j = 1; j < 3; ++j) {
        const float a0 = xp[j], a1 = xp[3 + j], a2 = xp[96 + j], a3 = xp[99 + j];
        float c, s;
        s = __builtin_amdgcn_sinf(a0 * 0.25f); c = __builtin_amdgcn_cosf(a0 * 0.25f);
        rx16<8>(sr, si, c, s);
        s = __builtin_amdgcn_sinf(a1 * 0.25f); c = __builtin_amdgcn_cosf(a1 * 0.25f);
        rx16<4>(sr, si, c, s);
        s = __builtin_amdgcn_sinf(a2 * 0.25f); c = __builtin_amdgcn_cosf(a2 * 0.25f);
        rx16<2>(sr, si, c, s);
        s = __builtin_amdgcn_sinf(a3 * 0.25f); c = __builtin_amdgcn_cosf(a3 * 0.25f);
        rx16<1>(sr, si, c, s);

        const float* p = pp + 5 * j;
        bcoef(p[0], br, bi); cx16<8, 4>(sr, si, br, bi);
        bcoef(p[1], br, bi); cx16<4, 2>(sr, si, br, bi);
        bcoef(p[2], br, bi); cx16<2, 1>(sr, si, br, bi);
        bcoef(p[3], br, bi); cx16<1, 8>(sr, si, br, bi);

        const float rev = p[4] * 0.5f;
        const float sl = __builtin_amdgcn_sinf(rev);
        const float cl = __builtin_amdgcn_cosf(rev);
        cz16(sr, si, h ? cl : 1.0f, h ? sl : 0.0f);
    }

    // <X0> = sum Re(conj(psi0)*psi1): symmetric in the lane pair -> both
    // lanes compute the same dot from partner values via shfl_xor(1).
    float dot = 0.0f;
#pragma unroll
    for (int m = 0; m < 16; ++m) {
        const float orr = __shfl_xor(sr[m], 1);
        const float oii = __shfl_xor(si[m], 1);
        dot = fmaf(sr[m], orr, fmaf(si[m], oii, dot));
    }

    // acos(x)/pi via A&S 4.4.45: acos(a) ~= sqrt(1-a)*P(a), a=|x|; err<6.7e-5 rad
    float x = fminf(fmaxf(dot, -1.0f + 1e-5f), 1.0f - 1e-5f);
    const float a  = fabsf(x);
    const float sq = __builtin_amdgcn_sqrtf(1.0f - a);
    float pl = fmaf(a, -0.0187293f, 0.0742610f);
    pl = fmaf(a, pl, -0.2121144f);
    pl = fmaf(a, pl, 1.5707288f);
    float ac = sq * pl;
    if (x < 0.0f) ac = PI_F - ac;

    if (h == 0) out[sim] = ac * (1.0f / PI_F);
}

extern "C" void kernel_launch(void* const* d_in, const int* in_sizes, int n_in,
                              void* d_out, int out_size, void* d_ws, size_t ws_size,
                              hipStream_t stream) {
    const float* inp = (const float*)d_in[0];   // (32,32,32,3) fp32
    const float* ker = (const float*)d_in[1];   // (8,1,15)     fp32
    float* out = (float*)d_out;                 // (32,31,31,8) fp32
    const int nsim = out_size;                  // 246016
    const int total = nsim * 2;                 // 2 lanes per simulation
    const int block = 256;
    const int grid = (total + block - 1) / block;
    u1_split_kernel<<<grid, block, 0, stream>>>(inp, ker, out, nsim);
}

// Round 4
// 71.888 us; speedup vs baseline: 1.0098x; 1.0098x over previous
//
#include <hip/hip_runtime.h>
#include <math.h>

#define PI_F 3.14159265358979323846f

// All 16-amp states index qubits as: bit8=q1, bit4=q2, bit2=q3, bit1=q4.

// RX on stride-S qubit: [[c,-is],[-is,c]]
template<int S>
__device__ __forceinline__ void rx16(float* sr, float* si, float c, float s) {
#pragma unroll
    for (int i = 0; i < 16; ++i) {
        if (i & S) continue;
        const int j = i + S;
        const float r0 = sr[i], m0 = si[i], r1 = sr[j], m1 = si[j];
        sr[i] = fmaf(c, r0,  s * m1);
        si[i] = fmaf(c, m0, -s * r1);
        sr[j] = fmaf(c, r1,  s * m0);
        si[j] = fmaf(c, m1, -s * r0);
    }
}

// CX^e, control stride Sc, target stride St. B=(1-lam)/2; A+B=1:
// u = B*(a1-a0); new0 = a0+u; new1 = a1-u.
template<int Sc, int St>
__device__ __forceinline__ void cx16(float* sr, float* si, float br, float bi) {
#pragma unroll
    for (int i = 0; i < 16; ++i) {
        if (!(i & Sc) || (i & St)) continue;
        const int j = i + St;
        const float dr = sr[j] - sr[i], di = si[j] - si[i];
        const float ur = br * dr - bi * di;
        const float ui = fmaf(br, di, bi * dr);
        sr[i] += ur; si[i] += ui;
        sr[j] -= ur; si[j] -= ui;
    }
}

// CZ phase lam=(cl,sl) on q1=1 half (bit8) — applied to psi1 only.
__device__ __forceinline__ void cz16(float* sr, float* si, float cl, float sl) {
#pragma unroll
    for (int m = 0; m < 16; ++m) {
        if (!(m & 8)) continue;
        const float r = sr[m], q = si[m];
        sr[m] = r * cl - q * sl;
        si[m] = fmaf(r, sl, q * cl);
    }
}

// B = (1 - e^{i*pi*e})/2 via hw trig (revolutions: sin(pi*e) = v_sin(e/2)).
__device__ __forceinline__ void bcoef(float e, float& br, float& bi) {
    const float rev = e * 0.5f;
    const float sl = __builtin_amdgcn_sinf(rev);
    const float cl = __builtin_amdgcn_cosf(rev);
    br = 0.5f * (1.0f - cl);
    bi = -0.5f * sl;
}

// Cap VGPRs at 128 -> 4 blocks/CU -> all 961 blocks resident in one round.
__global__ __launch_bounds__(256, 4)
void u1_circuit_kernel(const float* __restrict__ inp,   // (32,32,32,3)
                       const float* __restrict__ ker,   // (8,1,15)
                       float* __restrict__ out,         // (32,31,31,8)
                       int total) {
    const int t = blockIdx.x * blockDim.x + threadIdx.x;
    if (t >= total) return;

    const int r   = t & 7;
    const int pix = t >> 3;
    const int iy  = pix % 31;
    const int tq  = pix / 31;
    const int ix  = tq % 31;
    const int b   = tq / 31;

    const float* xp = inp + ((size_t)(b * 32 + ix) * 32 + iy) * 3;
    const float* pp = ker + r * 15;

    // ---------- layer 0: RX product state on q1..q4 (q0 handled analytically)
    float c1, s1, c2, s2, c3, s3, c4, s4;
    {
        const float a0 = xp[0], a1 = xp[3], a2 = xp[96], a3 = xp[99];
        s1 = __builtin_amdgcn_sinf(a0 * 0.25f); c1 = __builtin_amdgcn_cosf(a0 * 0.25f);
        s2 = __builtin_amdgcn_sinf(a1 * 0.25f); c2 = __builtin_amdgcn_cosf(a1 * 0.25f);
        s3 = __builtin_amdgcn_sinf(a2 * 0.25f); c3 = __builtin_amdgcn_cosf(a2 * 0.25f);
        s4 = __builtin_amdgcn_sinf(a3 * 0.25f); c4 = __builtin_amdgcn_cosf(a3 * 0.25f);
    }
    float t2[4], t3[8], mg[16];
    t2[0] = c1 * c2; t2[1] = c1 * s2; t2[2] = s1 * c2; t2[3] = s1 * s2;
#pragma unroll
    for (int x = 0; x < 8; ++x)  t3[x] = t2[x >> 1] * ((x & 1) ? s3 : c3);
#pragma unroll
    for (int x = 0; x < 16; ++x) mg[x] = t3[x >> 1] * ((x & 1) ? s4 : c4);

    // amp[m] = (-i)^popcount(m) * mg[m]  (zero pattern folds into first cx16)
    float p0r[16], p0i[16];
#pragma unroll
    for (int m = 0; m < 16; ++m) {
        const int pc = __builtin_popcount(m) & 3;
        p0r[m] = (pc == 0) ? mg[m] : ((pc == 2) ? -mg[m] : 0.0f);
        p0i[m] = (pc == 1) ? -mg[m] : ((pc == 3) ? mg[m] : 0.0f);
    }

    float br, bi;
    bcoef(pp[0], br, bi); cx16<8, 4>(p0r, p0i, br, bi);
    bcoef(pp[1], br, bi); cx16<4, 2>(p0r, p0i, br, bi);
    bcoef(pp[2], br, bi); cx16<2, 1>(p0r, p0i, br, bi);
    bcoef(pp[3], br, bi); cx16<1, 8>(p0r, p0i, br, bi);

    // first CZ: psi1 = psi0 with phase lam on q1=1 half; psi0 unchanged.
    float p1r[16], p1i[16];
    {
        const float rev = pp[4] * 0.5f;
        const float sl = __builtin_amdgcn_sinf(rev);
        const float cl = __builtin_amdgcn_cosf(rev);
#pragma unroll
        for (int m = 0; m < 16; ++m) {
            if (m & 8) {
                p1r[m] = p0r[m] * cl - p0i[m] * sl;
                p1i[m] = fmaf(p0r[m], sl, p0i[m] * cl);
            } else {
                p1r[m] = p0r[m];
                p1i[m] = p0i[m];
            }
        }
    }

    // ---------- layers 1..2: same RX/CX on both halves; CZ phases psi1 only
#pragma unroll
    for (int j = 1; j < 3; ++j) {
        const float a0 = xp[j], a1 = xp[3 + j], a2 = xp[96 + j], a3 = xp[99 + j];
        float c, s;
        s = __builtin_amdgcn_sinf(a0 * 0.25f); c = __builtin_amdgcn_cosf(a0 * 0.25f);
        rx16<8>(p0r, p0i, c, s); rx16<8>(p1r, p1i, c, s);
        s = __builtin_amdgcn_sinf(a1 * 0.25f); c = __builtin_amdgcn_cosf(a1 * 0.25f);
        rx16<4>(p0r, p0i, c, s); rx16<4>(p1r, p1i, c, s);
        s = __builtin_amdgcn_sinf(a2 * 0.25f); c = __builtin_amdgcn_cosf(a2 * 0.25f);
        rx16<2>(p0r, p0i, c, s); rx16<2>(p1r, p1i, c, s);
        s = __builtin_amdgcn_sinf(a3 * 0.25f); c = __builtin_amdgcn_cosf(a3 * 0.25f);
        rx16<1>(p0r, p0i, c, s); rx16<1>(p1r, p1i, c, s);

        const float* p = pp + 5 * j;
        bcoef(p[0], br, bi); cx16<8, 4>(p0r, p0i, br, bi); cx16<8, 4>(p1r, p1i, br, bi);
        bcoef(p[1], br, bi); cx16<4, 2>(p0r, p0i, br, bi); cx16<4, 2>(p1r, p1i, br, bi);
        bcoef(p[2], br, bi); cx16<2, 1>(p0r, p0i, br, bi); cx16<2, 1>(p1r, p1i, br, bi);
        bcoef(p[3], br, bi); cx16<1, 8>(p0r, p0i, br, bi); cx16<1, 8>(p1r, p1i, br, bi);

        const float rev = p[4] * 0.5f;
        cz16(p1r, p1i, __builtin_amdgcn_cosf(rev), __builtin_amdgcn_sinf(rev));
    }

    // <X0> = sum Re(conj(psi0)*psi1)  (the two 1/sqrt2 factors cancel the 2x)
    float dot = 0.0f;
#pragma unroll
    for (int m = 0; m < 16; ++m)
        dot = fmaf(p0r[m], p1r[m], fmaf(p0i[m], p1i[m], dot));

    // acos(x)/pi via A&S 4.4.45: err < 6.7e-5 rad (2e-5 after /pi)
    float x = fminf(fmaxf(dot, -1.0f + 1e-5f), 1.0f - 1e-5f);
    const float a  = fabsf(x);
    const float sq = __builtin_amdgcn_sqrtf(1.0f - a);
    float pl = fmaf(a, -0.0187293f, 0.0742610f);
    pl = fmaf(a, pl, -0.2121144f);
    pl = fmaf(a, pl, 1.5707288f);
    float ac = sq * pl;
    if (x < 0.0f) ac = PI_F - ac;

    out[t] = ac * (1.0f / PI_F);
}

extern "C" void kernel_launch(void* const* d_in, const int* in_sizes, int n_in,
                              void* d_out, int out_size, void* d_ws, size_t ws_size,
                              hipStream_t stream) {
    const float* inp = (const float*)d_in[0];   // (32,32,32,3) fp32
    const float* ker = (const float*)d_in[1];   // (8,1,15)     fp32
    float* out = (float*)d_out;                 // (32,31,31,8) fp32
    const int total = out_size;                 // 246016
    const int block = 256;
    const int grid = (total + block - 1) / block;
    u1_circuit_kernel<<<grid, block, 0, stream>>>(inp, ker, out, total);
}

// Round 5
// 70.161 us; speedup vs baseline: 1.0347x; 1.0246x over previous
//
#include <hip/hip_runtime.h>
#include <math.h>

#define PI_F 3.14159265358979323846f

// 16-amp half-states; qubit bits: 8=q1, 4=q2, 2=q3, 1=q4.

// RX on stride-S qubit: [[c,-is],[-is,c]]
template<int S>
__device__ __forceinline__ void rx16(float* sr, float* si, float c, float s) {
#pragma unroll
    for (int i = 0; i < 16; ++i) {
        if (i & S) continue;
        const int j = i + S;
        const float r0 = sr[i], m0 = si[i], r1 = sr[j], m1 = si[j];
        sr[i] = fmaf(c, r0,  s * m1);
        si[i] = fmaf(c, m0, -s * r1);
        sr[j] = fmaf(c, r1,  s * m0);
        si[j] = fmaf(c, m1, -s * r0);
    }
}

// CX^e, control stride Sc, target stride St. B=(1-lam)/2; A+B=1:
// u = B*(a1-a0); new0 = a0+u; new1 = a1-u.
template<int Sc, int St>
__device__ __forceinline__ void cx16(float* sr, float* si, float br, float bi) {
#pragma unroll
    for (int i = 0; i < 16; ++i) {
        if (!(i & Sc) || (i & St)) continue;
        const int j = i + St;
        const float dr = sr[j] - sr[i], di = si[j] - si[i];
        const float ur = br * dr - bi * di;
        const float ui = fmaf(br, di, bi * dr);
        sr[i] += ur; si[i] += ui;
        sr[j] -= ur; si[j] -= ui;
    }
}

// Phase (cl,sl) on the q1=1 half (bit 8).
__device__ __forceinline__ void cz16(float* sr, float* si, float cl, float sl) {
#pragma unroll
    for (int m = 0; m < 16; ++m) {
        if (!(m & 8)) continue;
        const float r = sr[m], q = si[m];
        sr[m] = r * cl - q * sl;
        si[m] = fmaf(r, sl, q * cl);
    }
}

// B = (1 - e^{i*pi*e})/2 via hw trig (revolutions: sin(pi*e) = v_sin(e/2)).
__device__ __forceinline__ void bcoef(float e, float& br, float& bi) {
    const float rev = e * 0.5f;
    const float sl = __builtin_amdgcn_sinf(rev);
    const float cl = __builtin_amdgcn_cosf(rev);
    br = 0.5f * (1.0f - cl);
    bi = -0.5f * sl;
}

// acos(x)/pi, A&S 4.4.45 (err < 6.7e-5 rad).
__device__ __forceinline__ float acos_over_pi(float dot) {
    float x = fminf(fmaxf(dot, -1.0f + 1e-5f), 1.0f - 1e-5f);
    const float a  = fabsf(x);
    const float sq = __builtin_amdgcn_sqrtf(1.0f - a);
    float pl = fmaf(a, -0.0187293f, 0.0742610f);
    pl = fmaf(a, pl, -0.2121144f);
    pl = fmaf(a, pl, 1.5707288f);
    float ac = sq * pl;
    if (x < 0.0f) ac = PI_F - ac;
    return ac * (1.0f / PI_F);
}

// One thread simulates TWO sims (same pixel, param rows r0 and r0+1):
// 2x independent gate chains per thread for ILP, half the wave count
// (1922 single-wave blocks -> one dispatch round at >=2 waves/SIMD).
__global__ __launch_bounds__(64, 2)
void u1_dual_kernel(const float* __restrict__ inp,   // (32,32,32,3)
                    const float* __restrict__ ker,   // (8,1,15)
                    float* __restrict__ out) {       // (32,31,31,8)
    const int g = blockIdx.x * 64 + threadIdx.x;     // pair index (exact grid)

    const int pix = g >> 2;            // sim = pix*8 + r ; this thread: r0, r0+1
    const int r0  = (g & 3) << 1;
    const int iy  = pix % 31;
    const int tq  = pix / 31;
    const int ix  = tq % 31;
    const int b   = tq / 31;

    const float* xp = inp + ((size_t)(b * 32 + ix) * 32 + iy) * 3;
    const float* pA = ker + r0 * 15;
    const float* pB = pA + 15;

    // ---------- layer 0 (shared between the two sims): RX product state
    float c1, s1, c2, s2, c3, s3, c4, s4;
    {
        const float a0 = xp[0], a1 = xp[3], a2 = xp[96], a3 = xp[99];
        s1 = __builtin_amdgcn_sinf(a0 * 0.25f); c1 = __builtin_amdgcn_cosf(a0 * 0.25f);
        s2 = __builtin_amdgcn_sinf(a1 * 0.25f); c2 = __builtin_amdgcn_cosf(a1 * 0.25f);
        s3 = __builtin_amdgcn_sinf(a2 * 0.25f); c3 = __builtin_amdgcn_cosf(a2 * 0.25f);
        s4 = __builtin_amdgcn_sinf(a3 * 0.25f); c4 = __builtin_amdgcn_cosf(a3 * 0.25f);
    }
    float t2[4], t3[8], mg[16];
    t2[0] = c1 * c2; t2[1] = c1 * s2; t2[2] = s1 * c2; t2[3] = s1 * s2;
#pragma unroll
    for (int x = 0; x < 8; ++x)  t3[x] = t2[x >> 1] * ((x & 1) ? s3 : c3);
#pragma unroll
    for (int x = 0; x < 16; ++x) mg[x] = t3[x >> 1] * ((x & 1) ? s4 : c4);

    // amp[m] = (-i)^popcount(m) * mg[m]; identical init for both sims
    // (zero pattern constant-folds into the first cx16 of each sim).
    float A0r[16], A0i[16], B0r[16], B0i[16];
#pragma unroll
    for (int m = 0; m < 16; ++m) {
        const int pc = __builtin_popcount(m) & 3;
        const float vr = (pc == 0) ? mg[m] : ((pc == 2) ? -mg[m] : 0.0f);
        const float vi = (pc == 1) ? -mg[m] : ((pc == 3) ? mg[m] : 0.0f);
        A0r[m] = vr; A0i[m] = vi;
        B0r[m] = vr; B0i[m] = vi;
    }

    float br, bi;
    // sim A layer-0 entanglers
    bcoef(pA[0], br, bi); cx16<8, 4>(A0r, A0i, br, bi);
    bcoef(pA[1], br, bi); cx16<4, 2>(A0r, A0i, br, bi);
    bcoef(pA[2], br, bi); cx16<2, 1>(A0r, A0i, br, bi);
    bcoef(pA[3], br, bi); cx16<1, 8>(A0r, A0i, br, bi);
    // sim B layer-0 entanglers
    bcoef(pB[0], br, bi); cx16<8, 4>(B0r, B0i, br, bi);
    bcoef(pB[1], br, bi); cx16<4, 2>(B0r, B0i, br, bi);
    bcoef(pB[2], br, bi); cx16<2, 1>(B0r, B0i, br, bi);
    bcoef(pB[3], br, bi); cx16<1, 8>(B0r, B0i, br, bi);

    // first CZ: psi1 = psi0 with phase on q1=1 half; psi0 unchanged.
    float A1r[16], A1i[16], B1r[16], B1i[16];
    {
        const float revA = pA[4] * 0.5f;
        const float slA = __builtin_amdgcn_sinf(revA);
        const float clA = __builtin_amdgcn_cosf(revA);
        const float revB = pB[4] * 0.5f;
        const float slB = __builtin_amdgcn_sinf(revB);
        const float clB = __builtin_amdgcn_cosf(revB);
#pragma unroll
        for (int m = 0; m < 16; ++m) {
            if (m & 8) {
                A1r[m] = A0r[m] * clA - A0i[m] * slA;
                A1i[m] = fmaf(A0r[m], slA, A0i[m] * clA);
                B1r[m] = B0r[m] * clB - B0i[m] * slB;
                B1i[m] = fmaf(B0r[m], slB, B0i[m] * clB);
            } else {
                A1r[m] = A0r[m]; A1i[m] = A0i[m];
                B1r[m] = B0r[m]; B1i[m] = B0i[m];
            }
        }
    }

    // ---------- layers 1..2: shared RX coefs; per-sim entangler coefs
#pragma unroll
    for (int j = 1; j < 3; ++j) {
        const float a0 = xp[j], a1 = xp[3 + j], a2 = xp[96 + j], a3 = xp[99 + j];
        float c, s;
        s = __builtin_amdgcn_sinf(a0 * 0.25f); c = __builtin_amdgcn_cosf(a0 * 0.25f);
        rx16<8>(A0r, A0i, c, s); rx16<8>(B0r, B0i, c, s);
        rx16<8>(A1r, A1i, c, s); rx16<8>(B1r, B1i, c, s);
        s = __builtin_amdgcn_sinf(a1 * 0.25f); c = __builtin_amdgcn_cosf(a1 * 0.25f);
        rx16<4>(A0r, A0i, c, s); rx16<4>(B0r, B0i, c, s);
        rx16<4>(A1r, A1i, c, s); rx16<4>(B1r, B1i, c, s);
        s = __builtin_amdgcn_sinf(a2 * 0.25f); c = __builtin_amdgcn_cosf(a2 * 0.25f);
        rx16<2>(A0r, A0i, c, s); rx16<2>(B0r, B0i, c, s);
        rx16<2>(A1r, A1i, c, s); rx16<2>(B1r, B1i, c, s);
        s = __builtin_amdgcn_sinf(a3 * 0.25f); c = __builtin_amdgcn_cosf(a3 * 0.25f);
        rx16<1>(A0r, A0i, c, s); rx16<1>(B0r, B0i, c, s);
        rx16<1>(A1r, A1i, c, s); rx16<1>(B1r, B1i, c, s);

        const float* qA = pA + 5 * j;
        const float* qB = pB + 5 * j;
        float brA, biA, brB, biB;
        bcoef(qA[0], brA, biA); bcoef(qB[0], brB, biB);
        cx16<8, 4>(A0r, A0i, brA, biA); cx16<8, 4>(A1r, A1i, brA, biA);
        cx16<8, 4>(B0r, B0i, brB, biB); cx16<8, 4>(B1r, B1i, brB, biB);
        bcoef(qA[1], brA, biA); bcoef(qB[1], brB, biB);
        cx16<4, 2>(A0r, A0i, brA, biA); cx16<4, 2>(A1r, A1i, brA, biA);
        cx16<4, 2>(B0r, B0i, brB, biB); cx16<4, 2>(B1r, B1i, brB, biB);
        bcoef(qA[2], brA, biA); bcoef(qB[2], brB, biB);
        cx16<2, 1>(A0r, A0i, brA, biA); cx16<2, 1>(A1r, A1i, brA, biA);
        cx16<2, 1>(B0r, B0i, brB, biB); cx16<2, 1>(B1r, B1i, brB, biB);
        bcoef(qA[3], brA, biA); bcoef(qB[3], brB, biB);
        cx16<1, 8>(A0r, A0i, brA, biA); cx16<1, 8>(A1r, A1i, brA, biA);
        cx16<1, 8>(B0r, B0i, brB, biB); cx16<1, 8>(B1r, B1i, brB, biB);

        const float revA = qA[4] * 0.5f;
        cz16(A1r, A1i, __builtin_amdgcn_cosf(revA), __builtin_amdgcn_sinf(revA));
        const float revB = qB[4] * 0.5f;
        cz16(B1r, B1i, __builtin_amdgcn_cosf(revB), __builtin_amdgcn_sinf(revB));
    }

    // <X0> = sum Re(conj(psi0)*psi1) per sim (1/sqrt2 factors cancel the 2x)
    float dotA = 0.0f, dotB = 0.0f;
#pragma unroll
    for (int m = 0; m < 16; ++m) {
        dotA = fmaf(A0r[m], A1r[m], fmaf(A0i[m], A1i[m], dotA));
        dotB = fmaf(B0r[m], B1r[m], fmaf(B0i[m], B1i[m], dotB));
    }

    float2 res;
    res.x = acos_over_pi(dotA);
    res.y = acos_over_pi(dotB);
    // sims 2g, 2g+1 are consecutive in out; 8-byte aligned (2g even).
    *(float2*)(out + 2 * (size_t)g) = res;
}

extern "C" void kernel_launch(void* const* d_in, const int* in_sizes, int n_in,
                              void* d_out, int out_size, void* d_ws, size_t ws_size,
                              hipStream_t stream) {
    const float* inp = (const float*)d_in[0];   // (32,32,32,3) fp32
    const float* ker = (const float*)d_in[1];   // (8,1,15)     fp32
    float* out = (float*)d_out;                 // (32,31,31,8) fp32
    const int npair = out_size / 2;             // 123008 = 64 * 1922 exactly
    const int block = 64;
    const int grid  = npair / block;            // 1922, exact fit
    u1_dual_kernel<<<grid, block, 0, stream>>>(inp, ker, out);
}

// Round 6
// 64.557 us; speedup vs baseline: 1.1245x; 1.0868x over previous
//
#include <hip/hip_runtime.h>
#include <math.h>

#define PI_F 3.14159265358979323846f

typedef float v2 __attribute__((ext_vector_type(2)));

__device__ __forceinline__ v2 sp(float x) { v2 r; r.x = x; r.y = x; return r; }
__device__ __forceinline__ v2 vfma(v2 a, v2 b, v2 c) {
    return __builtin_elementwise_fma(a, b, c);
}

// State: 16 complex amps per half, packed along q4: pack k holds amps m=2k,2k+1.
// k bits: 4=q1, 2=q2, 1=q3; pack element = q4.

// RX on k-stride Sk qubit (q1:4, q2:2, q3:1): element-wise on packs.
template<int Sk>
__device__ __forceinline__ void rx_pk(v2* R, v2* I, v2 c, v2 s, v2 ns) {
#pragma unroll
    for (int k = 0; k < 8; ++k) {
        if (k & Sk) continue;
        const int j = k + Sk;
        const v2 r0 = R[k], i0 = I[k], r1 = R[j], i1 = I[j];
        R[k] = vfma(c, r0, s * i1);
        I[k] = vfma(c, i0, ns * r1);
        R[j] = vfma(c, r1, s * i0);
        I[j] = vfma(c, i1, ns * r0);
    }
}

// RX on q4: partner is the other pack element -> .yx swizzle (folds to op_sel).
__device__ __forceinline__ void rx_q4(v2* R, v2* I, v2 c, v2 s, v2 ns) {
#pragma unroll
    for (int k = 0; k < 8; ++k) {
        const v2 r = R[k], i = I[k];
        R[k] = vfma(c, r, s * i.yx);
        I[k] = vfma(c, i, ns * r.yx);
    }
}

// CX^e with control k-bit Sck, target k-bit Stk. u = B*(a1-a0); a0+=u; a1-=u.
template<int Sck, int Stk>
__device__ __forceinline__ void cx_pk(v2* R, v2* I, v2 br, v2 bi, v2 nbi) {
#pragma unroll
    for (int k = 0; k < 8; ++k) {
        if (!(k & Sck) || (k & Stk)) continue;
        const int j = k + Stk;
        const v2 dr = R[j] - R[k], di = I[j] - I[k];
        const v2 ur = vfma(br, dr, nbi * di);
        const v2 ui = vfma(br, di, bi * dr);
        R[k] += ur; I[k] += ui;
        R[j] -= ur; I[j] -= ui;
    }
}

// CX^e control q3 (k-bit 1), target q4 (pack element): d=(a1-a0,a0-a1) via .yx,
// so u-vector carries (u,-u) and one pk_add applies both halves.
__device__ __forceinline__ void cx_q3q4(v2* R, v2* I, v2 br, v2 bi, v2 nbi) {
#pragma unroll
    for (int k = 1; k < 8; k += 2) {
        const v2 dr = R[k].yx - R[k], di = I[k].yx - I[k];
        const v2 ur = vfma(br, dr, nbi * di);
        const v2 ui = vfma(br, di, bi * dr);
        R[k] += ur; I[k] += ui;
    }
}

// CX^e control q4 (pack element 1), target q1 (k-bit 4): mask folded into the
// coefficient: brm=(0,br), bim=(0,bi) -> element 0 gets u=0.
__device__ __forceinline__ void cx_q4q1(v2* R, v2* I, v2 brm, v2 bim, v2 nbim) {
#pragma unroll
    for (int k = 0; k < 4; ++k) {
        const int j = k + 4;
        const v2 dr = R[j] - R[k], di = I[j] - I[k];
        const v2 ur = vfma(brm, dr, nbim * di);
        const v2 ui = vfma(brm, di, bim * dr);
        R[k] += ur; I[k] += ui;
        R[j] -= ur; I[j] -= ui;
    }
}

// Phase lam=(cl,sl) on q1=1 packs (k>=4) — applied to psi1 only.
__device__ __forceinline__ void cz_pk(v2* R, v2* I, v2 cl, v2 sl, v2 nsl) {
#pragma unroll
    for (int k = 4; k < 8; ++k) {
        const v2 r = R[k], i = I[k];
        R[k] = vfma(cl, r, nsl * i);
        I[k] = vfma(sl, r, cl * i);
    }
}

// B = (1 - e^{i*pi*e})/2 via hw trig (revolutions: sin(pi*e) = v_sin(e/2)).
__device__ __forceinline__ void bcoef(float e, float& br, float& bi) {
    const float rev = e * 0.5f;
    const float sl = __builtin_amdgcn_sinf(rev);
    const float cl = __builtin_amdgcn_cosf(rev);
    br = 0.5f * (1.0f - cl);
    bi = -0.5f * sl;
}

// No min-waves bound: round 4/5 proved VGPR caps force spills (WRITE_SIZE 12.5MB).
__global__ __launch_bounds__(256)
void u1_pk_kernel(const float* __restrict__ inp,   // (32,32,32,3)
                  const float* __restrict__ ker,   // (8,1,15)
                  float* __restrict__ out,         // (32,31,31,8)
                  int total) {
    const int t = blockIdx.x * blockDim.x + threadIdx.x;
    if (t >= total) return;

    const int r   = t & 7;
    const int pix = t >> 3;
    const int iy  = pix % 31;
    const int tq  = pix / 31;
    const int ix  = tq % 31;
    const int b   = tq / 31;

    const float* xp = inp + ((size_t)(b * 32 + ix) * 32 + iy) * 3;
    const float* pp = ker + r * 15;

    // ---------- layer 0: RX product state on q1..q4 (q0 analytic)
    float c1, s1, c2, s2, c3, s3, c4, s4;
    {
        const float a0 = xp[0], a1 = xp[3], a2 = xp[96], a3 = xp[99];
        s1 = __builtin_amdgcn_sinf(a0 * 0.25f); c1 = __builtin_amdgcn_cosf(a0 * 0.25f);
        s2 = __builtin_amdgcn_sinf(a1 * 0.25f); c2 = __builtin_amdgcn_cosf(a1 * 0.25f);
        s3 = __builtin_amdgcn_sinf(a2 * 0.25f); c3 = __builtin_amdgcn_cosf(a2 * 0.25f);
        s4 = __builtin_amdgcn_sinf(a3 * 0.25f); c4 = __builtin_amdgcn_cosf(a3 * 0.25f);
    }
    float t2[4], t3[8];
    t2[0] = c1 * c2; t2[1] = c1 * s2; t2[2] = s1 * c2; t2[3] = s1 * s2;
#pragma unroll
    for (int x = 0; x < 8; ++x) t3[x] = t2[x >> 1] * ((x & 1) ? s3 : c3);
    v2 cs4; cs4.x = c4; cs4.y = s4;

    // amp(m) = (-i)^popcount(m) * mag(m); per pack, elem0 pc=pc(k), elem1 pc(k)+1
    // => exactly one real and one imag component per pack.
    v2 R0[8], I0[8], R1[8], I1[8];
#pragma unroll
    for (int k = 0; k < 8; ++k) {
        const int pc = __builtin_popcount(k) & 3;
        const v2 mg = cs4 * sp(t3[k]);
        v2 rr, ii;
        if (pc == 0)      { rr.x =  mg.x; rr.y = 0.0f;  ii.x = 0.0f;  ii.y = -mg.y; }
        else if (pc == 1) { rr.x = 0.0f;  rr.y = -mg.y; ii.x = -mg.x; ii.y = 0.0f;  }
        else if (pc == 2) { rr.x = -mg.x; rr.y = 0.0f;  ii.x = 0.0f;  ii.y =  mg.y; }
        else              { rr.x = 0.0f;  rr.y =  mg.y; ii.x =  mg.x; ii.y = 0.0f;  }
        R0[k] = rr; I0[k] = ii;
    }

    float br, bi;
    bcoef(pp[0], br, bi); cx_pk<4, 2>(R0, I0, sp(br), sp(bi), sp(-bi));
    bcoef(pp[1], br, bi); cx_pk<2, 1>(R0, I0, sp(br), sp(bi), sp(-bi));
    bcoef(pp[2], br, bi); cx_q3q4 (R0, I0, sp(br), sp(bi), sp(-bi));
    {   // q4 -> q1 with element-masked coefficient
        bcoef(pp[3], br, bi);
        v2 brm, bim, nbim;
        brm.x = 0.0f; brm.y = br;
        bim.x = 0.0f; bim.y = bi;
        nbim.x = 0.0f; nbim.y = -bi;
        cx_q4q1(R0, I0, brm, bim, nbim);
    }

    // first CZ: psi1 = psi0 with phase on q1=1 packs; psi0 unchanged.
    {
        const float rev = pp[4] * 0.5f;
        const float sl = __builtin_amdgcn_sinf(rev);
        const float cl = __builtin_amdgcn_cosf(rev);
        const v2 clv = sp(cl), slv = sp(sl), nslv = sp(-sl);
#pragma unroll
        for (int k = 0; k < 4; ++k) { R1[k] = R0[k]; I1[k] = I0[k]; }
#pragma unroll
        for (int k = 4; k < 8; ++k) {
            R1[k] = vfma(clv, R0[k], nslv * I0[k]);
            I1[k] = vfma(slv, R0[k], clv * I0[k]);
        }
    }

    // ---------- layers 1..2: identical RX/CX on both halves; CZ on psi1 only
#pragma unroll
    for (int j = 1; j < 3; ++j) {
        const float a0 = xp[j], a1 = xp[3 + j], a2 = xp[96 + j], a3 = xp[99 + j];
        float c, s;
        s = __builtin_amdgcn_sinf(a0 * 0.25f); c = __builtin_amdgcn_cosf(a0 * 0.25f);
        rx_pk<4>(R0, I0, sp(c), sp(s), sp(-s)); rx_pk<4>(R1, I1, sp(c), sp(s), sp(-s));
        s = __builtin_amdgcn_sinf(a1 * 0.25f); c = __builtin_amdgcn_cosf(a1 * 0.25f);
        rx_pk<2>(R0, I0, sp(c), sp(s), sp(-s)); rx_pk<2>(R1, I1, sp(c), sp(s), sp(-s));
        s = __builtin_amdgcn_sinf(a2 * 0.25f); c = __builtin_amdgcn_cosf(a2 * 0.25f);
        rx_pk<1>(R0, I0, sp(c), sp(s), sp(-s)); rx_pk<1>(R1, I1, sp(c), sp(s), sp(-s));
        s = __builtin_amdgcn_sinf(a3 * 0.25f); c = __builtin_amdgcn_cosf(a3 * 0.25f);
        rx_q4  (R0, I0, sp(c), sp(s), sp(-s)); rx_q4  (R1, I1, sp(c), sp(s), sp(-s));

        const float* p = pp + 5 * j;
        bcoef(p[0], br, bi);
        cx_pk<4, 2>(R0, I0, sp(br), sp(bi), sp(-bi));
        cx_pk<4, 2>(R1, I1, sp(br), sp(bi), sp(-bi));
        bcoef(p[1], br, bi);
        cx_pk<2, 1>(R0, I0, sp(br), sp(bi), sp(-bi));
        cx_pk<2, 1>(R1, I1, sp(br), sp(bi), sp(-bi));
        bcoef(p[2], br, bi);
        cx_q3q4(R0, I0, sp(br), sp(bi), sp(-bi));
        cx_q3q4(R1, I1, sp(br), sp(bi), sp(-bi));
        {
            bcoef(p[3], br, bi);
            v2 brm, bim, nbim;
            brm.x = 0.0f; brm.y = br;
            bim.x = 0.0f; bim.y = bi;
            nbim.x = 0.0f; nbim.y = -bi;
            cx_q4q1(R0, I0, brm, bim, nbim);
            cx_q4q1(R1, I1, brm, bim, nbim);
        }
        const float rev = p[4] * 0.5f;
        const float sl = __builtin_amdgcn_sinf(rev);
        const float cl = __builtin_amdgcn_cosf(rev);
        cz_pk(R1, I1, sp(cl), sp(sl), sp(-sl));
    }

    // <X0> = sum Re(conj(psi0)*psi1)  (1/sqrt2 factors cancel the 2x)
    v2 acc = sp(0.0f);
#pragma unroll
    for (int k = 0; k < 8; ++k)
        acc = vfma(R0[k], R1[k], vfma(I0[k], I1[k], acc));
    const float dot = acc.x + acc.y;

    // acos(x)/pi via A&S 4.4.45 (err < 6.7e-5 rad)
    float x = fminf(fmaxf(dot, -1.0f + 1e-5f), 1.0f - 1e-5f);
    const float a  = fabsf(x);
    const float sq = __builtin_amdgcn_sqrtf(1.0f - a);
    float pl = fmaf(a, -0.0187293f, 0.0742610f);
    pl = fmaf(a, pl, -0.2121144f);
    pl = fmaf(a, pl, 1.5707288f);
    float ac = sq * pl;
    if (x < 0.0f) ac = PI_F - ac;

    out[t] = ac * (1.0f / PI_F);
}

extern "C" void kernel_launch(void* const* d_in, const int* in_sizes, int n_in,
                              void* d_out, int out_size, void* d_ws, size_t ws_size,
                              hipStream_t stream) {
    const float* inp = (const float*)d_in[0];   // (32,32,32,3) fp32
    const float* ker = (const float*)d_in[1];   // (8,1,15)     fp32
    float* out = (float*)d_out;                 // (32,31,31,8) fp32
    const int total = out_size;                 // 246016 = 961 * 256 exactly
    const int block = 256;
    const int grid = (total + block - 1) / block;
    u1_pk_kernel<<<grid, block, 0, stream>>>(inp, ker, out, total);
}

// Round 7
// 64.195 us; speedup vs baseline: 1.1308x; 1.0056x over previous
//
#include <hip/hip_runtime.h>
#include <math.h>

#define PI_F 3.14159265358979323846f

typedef float v2 __attribute__((ext_vector_type(2)));

__device__ __forceinline__ v2 sp(float x) { v2 r; r.x = x; r.y = x; return r; }
__device__ __forceinline__ v2 vfma(v2 a, v2 b, v2 c) {
    return __builtin_elementwise_fma(a, b, c);
}

// State: 16 complex amps per half, packed along q4: pack k holds amps m=2k,2k+1.
// k bits: 4=q1, 2=q2, 1=q3; pack element = q4.

template<int Sk>
__device__ __forceinline__ void rx_pk(v2* R, v2* I, v2 c, v2 s, v2 ns) {
#pragma unroll
    for (int k = 0; k < 8; ++k) {
        if (k & Sk) continue;
        const int j = k + Sk;
        const v2 r0 = R[k], i0 = I[k], r1 = R[j], i1 = I[j];
        R[k] = vfma(c, r0, s * i1);
        I[k] = vfma(c, i0, ns * r1);
        R[j] = vfma(c, r1, s * i0);
        I[j] = vfma(c, i1, ns * r0);
    }
}

// RX on q4: partner is the other pack element (.yx folds to op_sel).
__device__ __forceinline__ void rx_q4(v2* R, v2* I, v2 c, v2 s, v2 ns) {
#pragma unroll
    for (int k = 0; k < 8; ++k) {
        const v2 r = R[k], i = I[k];
        R[k] = vfma(c, r, s * i.yx);
        I[k] = vfma(c, i, ns * r.yx);
    }
}

// CX^e with control k-bit Sck, target k-bit Stk. u = B*(a1-a0); a0+=u; a1-=u.
template<int Sck, int Stk>
__device__ __forceinline__ void cx_pk(v2* R, v2* I, v2 br, v2 bi, v2 nbi) {
#pragma unroll
    for (int k = 0; k < 8; ++k) {
        if (!(k & Sck) || (k & Stk)) continue;
        const int j = k + Stk;
        const v2 dr = R[j] - R[k], di = I[j] - I[k];
        const v2 ur = vfma(br, dr, nbi * di);
        const v2 ui = vfma(br, di, bi * dr);
        R[k] += ur; I[k] += ui;
        R[j] -= ur; I[j] -= ui;
    }
}

// CX^e control q3 (k-bit 1), target q4 (pack element): d=(a1-a0,a0-a1) via .yx.
__device__ __forceinline__ void cx_q3q4(v2* R, v2* I, v2 br, v2 bi, v2 nbi) {
#pragma unroll
    for (int k = 1; k < 8; k += 2) {
        const v2 dr = R[k].yx - R[k], di = I[k].yx - I[k];
        const v2 ur = vfma(br, dr, nbi * di);
        const v2 ui = vfma(br, di, bi * dr);
        R[k] += ur; I[k] += ui;
    }
}

// CX^e control q4 (pack element 1), target q1 (k-bit 4): mask in coefficient.
__device__ __forceinline__ void cx_q4q1(v2* R, v2* I, v2 brm, v2 bim, v2 nbim) {
#pragma unroll
    for (int k = 0; k < 4; ++k) {
        const int j = k + 4;
        const v2 dr = R[j] - R[k], di = I[j] - I[k];
        const v2 ur = vfma(brm, dr, nbim * di);
        const v2 ui = vfma(brm, di, bim * dr);
        R[k] += ur; I[k] += ui;
        R[j] -= ur; I[j] -= ui;
    }
}

// Phase lam=(cl,sl) on q1=1 packs (k>=4) — psi1 only.
__device__ __forceinline__ void cz_pk(v2* R, v2* I, v2 cl, v2 sl, v2 nsl) {
#pragma unroll
    for (int k = 4; k < 8; ++k) {
        const v2 r = R[k], i = I[k];
        R[k] = vfma(cl, r, nsl * i);
        I[k] = vfma(sl, r, cl * i);
    }
}

// Block = 32 pixels x 8 rows. Phase 1 fills LDS tables (504 entries, <=2 per
// thread); phase 2 is the r6 packed gate chain reading coefficients from LDS.
__global__ __launch_bounds__(256)
void u1_lds_kernel(const float* __restrict__ inp,   // (32,32,32,3)
                   const float* __restrict__ ker,   // (8,1,15)
                   float* __restrict__ out) {       // (32,31,31,8)
    const int tid = threadIdx.x;
    const int blockPix0 = blockIdx.x * 32;

    // trig[pl][j*4+c] = (cos, sin)(a*0.25) for pixel-local pl, channel j,
    // corner c (offsets {0,3,96,99}); coef[r][5j+g] = (br,bi) g<4, (cl,sl) g=4.
    __shared__ v2 trig[32][12];
    __shared__ v2 coef[8][15];

#pragma unroll
    for (int pass = 0; pass < 2; ++pass) {
        const int e = tid + pass * 256;
        if (e < 384) {
            const int pl = e / 12;
            const int s  = e % 12;
            const int j  = s >> 2;
            const int c  = s & 3;
            const int pix = blockPix0 + pl;
            const int iy = pix % 31;
            const int tq = pix / 31;
            const int ix = tq % 31;
            const int b  = tq / 31;
            const float a = inp[((size_t)(b * 32 + ix + (c >> 1)) * 32
                                 + (iy + (c & 1))) * 3 + j];
            v2 cs;
            cs.x = __builtin_amdgcn_cosf(a * 0.25f);
            cs.y = __builtin_amdgcn_sinf(a * 0.25f);
            trig[pl][s] = cs;
        } else if (e < 504) {
            const int ec = e - 384;
            const int r  = ec / 15;
            const int g  = ec % 15;
            const float p = ker[r * 15 + g];
            const float rev = p * 0.5f;
            const float cl = __builtin_amdgcn_cosf(rev);
            const float sl = __builtin_amdgcn_sinf(rev);
            v2 cf;
            if (g % 5 == 4) { cf.x = cl; cf.y = sl; }                  // CZ
            else { cf.x = 0.5f * (1.0f - cl); cf.y = -0.5f * sl; }     // CX B
            coef[r][g] = cf;
        }
    }
    __syncthreads();

    const int r  = tid & 7;
    const int pl = tid >> 3;
    const v2* T = trig[pl];
    const v2* Q = coef[r];

    // ---------- layer 0: RX product state on q1..q4 (q0 analytic)
    const v2 cs1 = T[0], cs2 = T[1], cs3 = T[2], cs4 = T[3];
    float t2[4], t3[8];
    t2[0] = cs1.x * cs2.x; t2[1] = cs1.x * cs2.y;
    t2[2] = cs1.y * cs2.x; t2[3] = cs1.y * cs2.y;
#pragma unroll
    for (int x = 0; x < 8; ++x) t3[x] = t2[x >> 1] * ((x & 1) ? cs3.y : cs3.x);

    // amp(m) = (-i)^popcount(m) * mag(m): one real + one imag elem per pack.
    v2 R0[8], I0[8], R1[8], I1[8];
#pragma unroll
    for (int k = 0; k < 8; ++k) {
        const int pc = __builtin_popcount(k) & 3;
        const v2 mg = cs4 * sp(t3[k]);
        v2 rr, ii;
        if (pc == 0)      { rr.x =  mg.x; rr.y = 0.0f;  ii.x = 0.0f;  ii.y = -mg.y; }
        else if (pc == 1) { rr.x = 0.0f;  rr.y = -mg.y; ii.x = -mg.x; ii.y = 0.0f;  }
        else if (pc == 2) { rr.x = -mg.x; rr.y = 0.0f;  ii.x = 0.0f;  ii.y =  mg.y; }
        else              { rr.x = 0.0f;  rr.y =  mg.y; ii.x =  mg.x; ii.y = 0.0f;  }
        R0[k] = rr; I0[k] = ii;
    }

    {
        v2 q;
        q = Q[0]; cx_pk<4, 2>(R0, I0, sp(q.x), sp(q.y), sp(-q.y));
        q = Q[1]; cx_pk<2, 1>(R0, I0, sp(q.x), sp(q.y), sp(-q.y));
        q = Q[2]; cx_q3q4 (R0, I0, sp(q.x), sp(q.y), sp(-q.y));
        q = Q[3];
        v2 brm, bim, nbim;
        brm.x = 0.0f; brm.y = q.x;
        bim.x = 0.0f; bim.y = q.y;
        nbim.x = 0.0f; nbim.y = -q.y;
        cx_q4q1(R0, I0, brm, bim, nbim);
    }

    // first CZ: psi1 = psi0 with phase on q1=1 packs; psi0 unchanged.
    {
        const v2 zq = Q[4];
        const v2 clv = sp(zq.x), slv = sp(zq.y), nslv = sp(-zq.y);
#pragma unroll
        for (int k = 0; k < 4; ++k) { R1[k] = R0[k]; I1[k] = I0[k]; }
#pragma unroll
        for (int k = 4; k < 8; ++k) {
            R1[k] = vfma(clv, R0[k], nslv * I0[k]);
            I1[k] = vfma(slv, R0[k], clv * I0[k]);
        }
    }

    // ---------- layers 1..2: identical RX/CX on both halves; CZ on psi1 only
#pragma unroll
    for (int j = 1; j < 3; ++j) {
        const v2* Tj = T + 4 * j;
        v2 cs;
        cs = Tj[0];
        rx_pk<4>(R0, I0, sp(cs.x), sp(cs.y), sp(-cs.y));
        rx_pk<4>(R1, I1, sp(cs.x), sp(cs.y), sp(-cs.y));
        cs = Tj[1];
        rx_pk<2>(R0, I0, sp(cs.x), sp(cs.y), sp(-cs.y));
        rx_pk<2>(R1, I1, sp(cs.x), sp(cs.y), sp(-cs.y));
        cs = Tj[2];
        rx_pk<1>(R0, I0, sp(cs.x), sp(cs.y), sp(-cs.y));
        rx_pk<1>(R1, I1, sp(cs.x), sp(cs.y), sp(-cs.y));
        cs = Tj[3];
        rx_q4  (R0, I0, sp(cs.x), sp(cs.y), sp(-cs.y));
        rx_q4  (R1, I1, sp(cs.x), sp(cs.y), sp(-cs.y));

        const v2* Qj = Q + 5 * j;
        v2 q;
        q = Qj[0];
        cx_pk<4, 2>(R0, I0, sp(q.x), sp(q.y), sp(-q.y));
        cx_pk<4, 2>(R1, I1, sp(q.x), sp(q.y), sp(-q.y));
        q = Qj[1];
        cx_pk<2, 1>(R0, I0, sp(q.x), sp(q.y), sp(-q.y));
        cx_pk<2, 1>(R1, I1, sp(q.x), sp(q.y), sp(-q.y));
        q = Qj[2];
        cx_q3q4(R0, I0, sp(q.x), sp(q.y), sp(-q.y));
        cx_q3q4(R1, I1, sp(q.x), sp(q.y), sp(-q.y));
        q = Qj[3];
        {
            v2 brm, bim, nbim;
            brm.x = 0.0f; brm.y = q.x;
            bim.x = 0.0f; bim.y = q.y;
            nbim.x = 0.0f; nbim.y = -q.y;
            cx_q4q1(R0, I0, brm, bim, nbim);
            cx_q4q1(R1, I1, brm, bim, nbim);
        }
        q = Qj[4];
        cz_pk(R1, I1, sp(q.x), sp(q.y), sp(-q.y));
    }

    // <X0> = sum Re(conj(psi0)*psi1)  (1/sqrt2 factors cancel the 2x)
    v2 acc = sp(0.0f);
#pragma unroll
    for (int k = 0; k < 8; ++k)
        acc = vfma(R0[k], R1[k], vfma(I0[k], I1[k], acc));
    const float dot = acc.x + acc.y;

    // acos(x)/pi via A&S 4.4.45 (err < 6.7e-5 rad)
    float x = fminf(fmaxf(dot, -1.0f + 1e-5f), 1.0f - 1e-5f);
    const float a  = fabsf(x);
    const float sq = __builtin_amdgcn_sqrtf(1.0f - a);
    float pq = fmaf(a, -0.0187293f, 0.0742610f);
    pq = fmaf(a, pq, -0.2121144f);
    pq = fmaf(a, pq, 1.5707288f);
    float ac = sq * pq;
    if (x < 0.0f) ac = PI_F - ac;

    out[blockIdx.x * 256 + tid] = ac * (1.0f / PI_F);
}

extern "C" void kernel_launch(void* const* d_in, const int* in_sizes, int n_in,
                              void* d_out, int out_size, void* d_ws, size_t ws_size,
                              hipStream_t stream) {
    const float* inp = (const float*)d_in[0];   // (32,32,32,3) fp32
    const float* ker = (const float*)d_in[1];   // (8,1,15)     fp32
    float* out = (float*)d_out;                 // (32,31,31,8) fp32
    const int grid = out_size / 256;            // 961, exact (246016 = 961*256)
    u1_lds_kernel<<<grid, 256, 0, stream>>>(inp, ker, out);
}